// Round 11
// baseline (105.614 us; speedup 1.0000x reference)
//
#include <hip/hip_runtime.h>
#include <hip/hip_bf16.h>

// QConv1d: x (8,64,16384) f32, w (64,64,9) f32, bias (64) f32
// out (8,64,16384) f32 = conv1d(x, w, pad=4) * 0.125 + bias
// Strategy: cast to bf16 (weights pre-scaled by 0.125 — exact, power of two),
// MFMA f32_16x16x32_bf16, fp32 accumulate, fp32 out.
// Round-15: single-kernel, BUILD-FIRST weight fragments. R10 (hoisted afr
// from w2) = 97.5, best. Remaining addressable cost: the w_rearrange
// dispatch + inter-kernel gap (~3-4 µs of window). Prior fusion failures
// are understood and avoided:
//   R3: wt transients + x-stage regs live together -> spill. Fix: build
//       afr[18] FIRST (wt dies before any x load issues), sched_barrier(0)
//       stops the compiler hoisting x loads into the build.
//   R6: build after the barrier -> serialized against compute. Fix: build
//       at kernel start; its ~0.4 µs hides nothing but replaces ~3 µs of
//       launch+gap+w_rearrange.
// Peak VGPR ~200 (<256, no spill; occupancy grid-pinned at 2 blocks/CU).
// Everything after the build is byte-identical to R10.
#define C_IN    64
#define L_IN    16384
#define O_OUT   64
#define KTAP    9
#define LTILE   256
#define ROWS    272      // LTILE + 16 halo rows (global l in [l0-8, l0+264))
#define RSTRIDE 72       // 64 + 8 pad (multiple of 8 -> 16B-aligned b128 rows)

typedef short          bf16x8 __attribute__((ext_vector_type(8)));   // MFMA A/B frag
typedef unsigned int   u32x4  __attribute__((ext_vector_type(4)));
typedef float          f32x4  __attribute__((ext_vector_type(4)));   // MFMA C/D frag

static __device__ __forceinline__ unsigned short f2bf(float f) {
  __hip_bfloat16 h = __float2bfloat16(f);   // round-to-nearest
  return __builtin_bit_cast(unsigned short, h);
}

// pack two floats -> one u32 of two bf16 (lo in low 16 bits)
static __device__ __forceinline__ unsigned int pk2(float lo, float hi) {
  return (unsigned int)f2bf(lo) | ((unsigned int)f2bf(hi) << 16);
}

// ---------------------------------------------------------------------------
// One block = one n, one 256-wide L tile, all 64 outputs. 4 waves, each
// owning 16 O rows; two 128-wide L halves computed sequentially with
// memory traffic overlapped against MFMA (T14 skeleton).
// ---------------------------------------------------------------------------
__global__ __launch_bounds__(256) void qconv_kernel(
    const float* __restrict__ x,
    const float* __restrict__ w,
    const float* __restrict__ bias,
    float* __restrict__ out) {

  __shared__ __align__(16) unsigned short xs[ROWS][RSTRIDE];  // bf16 x tile, [l][c]

  const int tid = threadIdx.x;
  const int n   = blockIdx.x >> 6;
  const int l0  = (blockIdx.x & 63) << 8;      // tile base along L
  const float* xn = x + (size_t)n * C_IN * L_IN;

  // ---- Phase 0: build A-frags from w (BEFORE any x traffic) -------------
  // Lane holds o = wave*16 + col; frag(t,k)[i] = bf16(w[o][k*32+quad*8+i][t]
  // * 0.125). w row = 576 contiguous floats; (k,quad) slice = 72 contiguous
  // floats, 16B-aligned. 36 pipelined L2 loads + 72 pk2; wt dies here.
  // (Layout verified correct in rounds 8/11: absmax unchanged.)
  const int wave = tid >> 6;
  const int lane = tid & 63;
  const int col  = lane & 15;
  const int quad = lane >> 4;
  const int o16  = (wave << 4) + col;

  bf16x8 afr[2 * KTAP];                // [t*2 + k] — 72 VGPR, live to end
  {
    const float* wrow = w + (size_t)o16 * (C_IN * KTAP);
#pragma unroll
    for (int k = 0; k < 2; ++k) {
      const float* wp = wrow + ((k << 5) + (quad << 3)) * KTAP;  // 72 floats
      f32x4 wt[18];
#pragma unroll
      for (int j = 0; j < 18; ++j)
        wt[j] = *reinterpret_cast<const f32x4*>(wp + 4 * j);
#pragma unroll
      for (int t = 0; t < KTAP; ++t) {
        u32x4 fr;
#pragma unroll
        for (int p = 0; p < 4; ++p) {
          const int e0 = (2 * p) * KTAP + t;
          const int e1 = (2 * p + 1) * KTAP + t;
          fr[p] = pk2(wt[e0 >> 2][e0 & 3] * 0.125f,
                      wt[e1 >> 2][e1 & 3] * 0.125f);
        }
        afr[(t << 1) + k] = __builtin_bit_cast(bf16x8, fr);
      }
    }
  }
  __builtin_amdgcn_sched_barrier(0);   // keep x loads below: wt must be dead first

  // ---- Issue phase: all global x loads for this tile --------------------
  const int ucb = tid & 7;            // channel block (c0 = ucb*8)
  const int ulb = tid >> 3;           // l block within region (0..31)
  const int uc0 = ucb << 3;

  // A unit 0 (rows ulb*4 .. +3)
  const int a0_gl0 = l0 - 8 + (ulb << 2);
  const bool a0_ok = (a0_gl0 >= 0) && (a0_gl0 + 4 <= L_IN);
  f32x4 va0[8];
  if (a0_ok) {
#pragma unroll
    for (int i = 0; i < 8; ++i)
      va0[i] = *reinterpret_cast<const f32x4*>(xn + (size_t)(uc0 + i) * L_IN + a0_gl0);
  }
  // A unit 1 (tid < 32): rows 128 + (tid>>3)*4 .. +3  — always in-bounds
  const bool have1 = (tid < 32);
  const int a1_gl0 = l0 - 8 + ((32 + ulb) << 2);   // only meaningful for tid<32
  f32x4 va1[8];
  if (have1) {
#pragma unroll
    for (int i = 0; i < 8; ++i)
      va1[i] = *reinterpret_cast<const f32x4*>(xn + (size_t)(uc0 + i) * L_IN + a1_gl0);
  }
  // B unit: rows 144 + ulb*4 .. +3 (gl0 >= 136 >= 0 always)
  const int b_gl0 = l0 + 136 + (ulb << 2);
  const bool b_ok = (b_gl0 + 4 <= L_IN);
  f32x4 vb[8];
  if (b_ok) {
#pragma unroll
    for (int i = 0; i < 8; ++i)
      vb[i] = *reinterpret_cast<const f32x4*>(xn + (size_t)(uc0 + i) * L_IN + b_gl0);
  }

  // ---- Convert + write half A to LDS ------------------------------------
  if (a0_ok) {
#pragma unroll
    for (int j = 0; j < 4; ++j) {
      u32x4 wv;
#pragma unroll
      for (int p = 0; p < 4; ++p)
        wv[p] = pk2(va0[2 * p][j], va0[2 * p + 1][j]);
      *reinterpret_cast<u32x4*>(&xs[(ulb << 2) + j][uc0]) = wv;
    }
  } else {
#pragma unroll
    for (int j = 0; j < 4; ++j) {
      const int gl = a0_gl0 + j;
      u32x4 wv;
#pragma unroll
      for (int p = 0; p < 4; ++p) {
        float lo = 0.f, hi = 0.f;
        if (gl >= 0 && gl < L_IN) {
          lo = xn[(size_t)(uc0 + 2 * p)     * L_IN + gl];
          hi = xn[(size_t)(uc0 + 2 * p + 1) * L_IN + gl];
        }
        wv[p] = pk2(lo, hi);
      }
      *reinterpret_cast<u32x4*>(&xs[(ulb << 2) + j][uc0]) = wv;
    }
  }
  if (have1) {
#pragma unroll
    for (int j = 0; j < 4; ++j) {
      u32x4 wv;
#pragma unroll
      for (int p = 0; p < 4; ++p)
        wv[p] = pk2(va1[2 * p][j], va1[2 * p + 1][j]);
      *reinterpret_cast<u32x4*>(&xs[128 + (ulb << 2) + j][uc0]) = wv;
    }
  }
  __syncthreads();

  // ---- Compute ----------------------------------------------------------
  const int obase = (wave << 4) + (quad << 2);
  float bv[4];
#pragma unroll
  for (int reg = 0; reg < 4; ++reg) bv[reg] = bias[obase + reg];

  f32x4 acc[8];
#pragma unroll
  for (int lt = 0; lt < 8; ++lt) acc[lt] = (f32x4){0.f, 0.f, 0.f, 0.f};

  // -- half A: out cols l0 .. l0+127; LDS rows r = col + t + 4 + lt*16 ----
#pragma unroll
  for (int t = 0; t < KTAP; ++t) {
#pragma unroll
    for (int k = 0; k < 2; ++k) {
      const bf16x8 a = afr[(t << 1) + k];
#pragma unroll
      for (int lt = 0; lt < 8; ++lt) {
        const int r = col + t + 4 + (lt << 4);
        const bf16x8 b = *reinterpret_cast<const bf16x8*>(&xs[r][(k << 5) + (quad << 3)]);
        acc[lt] = __builtin_amdgcn_mfma_f32_16x16x32_bf16(a, b, acc[lt], 0, 0, 0);
      }
    }
  }

  // ---- Convert + write half B to LDS (rows 144..271 — disjoint from the
  //      rows 4..139 compute-A just read, so no barrier needed above) -----
  if (b_ok) {
#pragma unroll
    for (int j = 0; j < 4; ++j) {
      u32x4 wv;
#pragma unroll
      for (int p = 0; p < 4; ++p)
        wv[p] = pk2(vb[2 * p][j], vb[2 * p + 1][j]);
      *reinterpret_cast<u32x4*>(&xs[144 + (ulb << 2) + j][uc0]) = wv;
    }
  } else {
#pragma unroll
    for (int j = 0; j < 4; ++j) {
      const int gl = b_gl0 + j;
      u32x4 wv;
#pragma unroll
      for (int p = 0; p < 4; ++p) {
        float lo = 0.f, hi = 0.f;
        if (gl < L_IN) {
          lo = xn[(size_t)(uc0 + 2 * p)     * L_IN + gl];
          hi = xn[(size_t)(uc0 + 2 * p + 1) * L_IN + gl];
        }
        wv[p] = pk2(lo, hi);
      }
      *reinterpret_cast<u32x4*>(&xs[144 + (ulb << 2) + j][uc0]) = wv;
    }
  }
  __syncthreads();

  // ---- store half A (global writes fly under compute-B) -----------------
#pragma unroll
  for (int lt = 0; lt < 8; ++lt) {
    const int l = l0 + (lt << 4) + col;
#pragma unroll
    for (int reg = 0; reg < 4; ++reg)
      out[((size_t)(n * O_OUT + obase + reg) << 14) + l] = acc[lt][reg] + bv[reg];
  }

  // -- half B: out cols l0+128 .. l0+255; rows r = 128 + col + t + 4 + lt*16
#pragma unroll
  for (int lt = 0; lt < 8; ++lt) acc[lt] = (f32x4){0.f, 0.f, 0.f, 0.f};

#pragma unroll
  for (int t = 0; t < KTAP; ++t) {
#pragma unroll
    for (int k = 0; k < 2; ++k) {
      const bf16x8 a = afr[(t << 1) + k];
#pragma unroll
      for (int lt = 0; lt < 8; ++lt) {
        const int r = 128 + col + t + 4 + (lt << 4);
        const bf16x8 b = *reinterpret_cast<const bf16x8*>(&xs[r][(k << 5) + (quad << 3)]);
        acc[lt] = __builtin_amdgcn_mfma_f32_16x16x32_bf16(a, b, acc[lt], 0, 0, 0);
      }
    }
  }

  // ---- store half B -----------------------------------------------------
#pragma unroll
  for (int lt = 0; lt < 8; ++lt) {
    const int l = l0 + 128 + (lt << 4) + col;
#pragma unroll
    for (int reg = 0; reg < 4; ++reg)
      out[((size_t)(n * O_OUT + obase + reg) << 14) + l] = acc[lt][reg] + bv[reg];
  }
}

extern "C" void kernel_launch(void* const* d_in, const int* in_sizes, int n_in,
                              void* d_out, int out_size, void* d_ws, size_t ws_size,
                              hipStream_t stream) {
  const float* x    = (const float*)d_in[0];
  const float* w    = (const float*)d_in[1];
  const float* bias = (const float*)d_in[2];
  float*       out  = (float*)d_out;
  (void)d_ws; (void)ws_size;

  // single fused dispatch: 8 n * 64 L-tiles = 512 blocks
  qconv_kernel<<<8 * (L_IN / LTILE), 256, 0, stream>>>(x, w, bias, out);
}

// Round 12
// 96.600 us; speedup vs baseline: 1.0933x; 1.0933x over previous
//
#include <hip/hip_runtime.h>
#include <hip/hip_bf16.h>

// QConv1d: x (8,64,16384) f32, w (64,64,9) f32, bias (64) f32
// out (8,64,16384) f32 = conv1d(x, w, pad=4) * 0.125 + bias
// Strategy: cast to bf16 (weights pre-scaled by 0.125 — exact, power of two),
// MFMA f32_16x16x32_bf16, fp32 accumulate, fp32 out.
// FINAL (round-16 = round-14 verbatim, the measured best at 97.47 µs).
// Structure: two-kernel (w_rearrange pre-pass + conv-as-GEMM), LTILE=256,
// 4 waves x 16 O, T14 async-stage split (half B reg-held through compute-A,
// store-A overlapped with compute-B), A-frags hoisted once into registers.
// Session evidence (11 rounds): every structural perturbation regresses —
//   smaller tile (+7), 8-wave (+6.5), fusion x3 (+5-8), m-pairing (+6),
//   XCD swizzle (0), T14-only (0). Warm body = 20.4 µs (double-dispatch
//   measurement, R7) vs ~12-16 µs latency-sum floor at the grid-pinned
//   2 waves/SIMD; the configuration is a sharp local optimum and the
//   residual is not addressable by any tested lever.
#define C_IN    64
#define L_IN    16384
#define O_OUT   64
#define KTAP    9
#define LTILE   256
#define ROWS    272      // LTILE + 16 halo rows (global l in [l0-8, l0+264))
#define RSTRIDE 72       // 64 + 8 pad (multiple of 8 -> 16B-aligned b128 rows)

typedef short          bf16x8 __attribute__((ext_vector_type(8)));   // MFMA A/B frag
typedef unsigned int   u32x4  __attribute__((ext_vector_type(4)));
typedef float          f32x4  __attribute__((ext_vector_type(4)));   // MFMA C/D frag

static __device__ __forceinline__ unsigned short f2bf(float f) {
  __hip_bfloat16 h = __float2bfloat16(f);   // round-to-nearest
  return __builtin_bit_cast(unsigned short, h);
}

// pack two floats -> one u32 of two bf16 (lo in low 16 bits)
static __device__ __forceinline__ unsigned int pk2(float lo, float hi) {
  return (unsigned int)f2bf(lo) | ((unsigned int)f2bf(hi) << 16);
}

// ---------------------------------------------------------------------------
// Pre-kernel: w[o][c][t] fp32 (stride-9 taps) -> W2[t][o][c] bf16 (c contig),
// pre-scaled by 0.125 (exact: power-of-two only touches the exponent).
// ---------------------------------------------------------------------------
__global__ void w_rearrange(const float* __restrict__ w,
                            unsigned short* __restrict__ w2) {
    int i = blockIdx.x * 256 + threadIdx.x;       // i = t*4096 + o*64 + c
    if (i >= KTAP * O_OUT * C_IN) return;
    int t  = i >> 12;
    int oc = i & 4095;                            // o*64 + c
    w2[i] = f2bf(w[oc * KTAP + t] * 0.125f);
}

// ---------------------------------------------------------------------------
// Main kernel: one block = one n, one 256-wide L tile, all 64 outputs.
// 4 waves, each owning 16 O rows; the two 128-wide L halves are computed
// sequentially with memory traffic overlapped against MFMA.
// ---------------------------------------------------------------------------
__global__ __launch_bounds__(256) void qconv_kernel(
    const float* __restrict__ x,
    const unsigned short* __restrict__ w2,    // bf16 bits, pre-scaled
    const float* __restrict__ bias,
    float* __restrict__ out) {

  __shared__ __align__(16) unsigned short xs[ROWS][RSTRIDE];  // bf16 x tile, [l][c]

  const int tid = threadIdx.x;
  const int n   = blockIdx.x >> 6;
  const int l0  = (blockIdx.x & 63) << 8;      // tile base along L
  const float* xn = x + (size_t)n * C_IN * L_IN;

  // ---- Issue phase: all global x loads for this tile --------------------
  const int ucb = tid & 7;            // channel block (c0 = ucb*8)
  const int ulb = tid >> 3;           // l block within region (0..31)
  const int uc0 = ucb << 3;

  // A unit 0 (rows ulb*4 .. +3)
  const int a0_gl0 = l0 - 8 + (ulb << 2);
  const bool a0_ok = (a0_gl0 >= 0) && (a0_gl0 + 4 <= L_IN);
  f32x4 va0[8];
  if (a0_ok) {
#pragma unroll
    for (int i = 0; i < 8; ++i)
      va0[i] = *reinterpret_cast<const f32x4*>(xn + (size_t)(uc0 + i) * L_IN + a0_gl0);
  }
  // A unit 1 (tid < 32): rows 128 + (tid>>3)*4 .. +3  — always in-bounds
  const bool have1 = (tid < 32);
  const int a1_gl0 = l0 - 8 + ((32 + ulb) << 2);   // only meaningful for tid<32
  f32x4 va1[8];
  if (have1) {
#pragma unroll
    for (int i = 0; i < 8; ++i)
      va1[i] = *reinterpret_cast<const f32x4*>(xn + (size_t)(uc0 + i) * L_IN + a1_gl0);
  }
  // B unit: rows 144 + ulb*4 .. +3 (gl0 >= 136 >= 0 always)
  const int b_gl0 = l0 + 136 + (ulb << 2);
  const bool b_ok = (b_gl0 + 4 <= L_IN);
  f32x4 vb[8];
  if (b_ok) {
#pragma unroll
    for (int i = 0; i < 8; ++i)
      vb[i] = *reinterpret_cast<const f32x4*>(xn + (size_t)(uc0 + i) * L_IN + b_gl0);
  }

  // ---- Hoisted A-frags: the 18 16B w2 fragments used by BOTH phases -----
  // (w2 is 72 KB, L2-resident; issued here so the latency hides under the
  // pack/write VALU below. +72 VGPR — free: grid pins 2 waves/SIMD, so
  // anything <=256 VGPR costs nothing.)
  const int wave = tid >> 6;
  const int lane = tid & 63;
  const int col  = lane & 15;
  const int quad = lane >> 4;
  const unsigned short* wbase = w2 + (((wave << 4) + col) << 6) + (quad << 3);

  bf16x8 afr[2 * KTAP];
#pragma unroll
  for (int t = 0; t < KTAP; ++t)
#pragma unroll
    for (int k = 0; k < 2; ++k)
      afr[(t << 1) + k] =
          *reinterpret_cast<const bf16x8*>(wbase + (t << 12) + (k << 5));

  // ---- Convert + write half A to LDS ------------------------------------
  if (a0_ok) {
#pragma unroll
    for (int j = 0; j < 4; ++j) {
      u32x4 wv;
#pragma unroll
      for (int p = 0; p < 4; ++p)
        wv[p] = pk2(va0[2 * p][j], va0[2 * p + 1][j]);
      *reinterpret_cast<u32x4*>(&xs[(ulb << 2) + j][uc0]) = wv;
    }
  } else {
#pragma unroll
    for (int j = 0; j < 4; ++j) {
      const int gl = a0_gl0 + j;
      u32x4 wv;
#pragma unroll
      for (int p = 0; p < 4; ++p) {
        float lo = 0.f, hi = 0.f;
        if (gl >= 0 && gl < L_IN) {
          lo = xn[(size_t)(uc0 + 2 * p)     * L_IN + gl];
          hi = xn[(size_t)(uc0 + 2 * p + 1) * L_IN + gl];
        }
        wv[p] = pk2(lo, hi);
      }
      *reinterpret_cast<u32x4*>(&xs[(ulb << 2) + j][uc0]) = wv;
    }
  }
  if (have1) {
#pragma unroll
    for (int j = 0; j < 4; ++j) {
      u32x4 wv;
#pragma unroll
      for (int p = 0; p < 4; ++p)
        wv[p] = pk2(va1[2 * p][j], va1[2 * p + 1][j]);
      *reinterpret_cast<u32x4*>(&xs[128 + (ulb << 2) + j][uc0]) = wv;
    }
  }
  __syncthreads();

  // ---- Compute ----------------------------------------------------------
  const int obase = (wave << 4) + (quad << 2);
  float bv[4];
#pragma unroll
  for (int reg = 0; reg < 4; ++reg) bv[reg] = bias[obase + reg];

  f32x4 acc[8];
#pragma unroll
  for (int lt = 0; lt < 8; ++lt) acc[lt] = (f32x4){0.f, 0.f, 0.f, 0.f};

  // -- half A: out cols l0 .. l0+127; LDS rows r = col + t + 4 + lt*16 ----
#pragma unroll
  for (int t = 0; t < KTAP; ++t) {
#pragma unroll
    for (int k = 0; k < 2; ++k) {
      const bf16x8 a = afr[(t << 1) + k];
#pragma unroll
      for (int lt = 0; lt < 8; ++lt) {
        const int r = col + t + 4 + (lt << 4);
        const bf16x8 b = *reinterpret_cast<const bf16x8*>(&xs[r][(k << 5) + (quad << 3)]);
        acc[lt] = __builtin_amdgcn_mfma_f32_16x16x32_bf16(a, b, acc[lt], 0, 0, 0);
      }
    }
  }

  // ---- Convert + write half B to LDS (rows 144..271 — disjoint from the
  //      rows 4..139 compute-A just read, so no barrier needed above) -----
  if (b_ok) {
#pragma unroll
    for (int j = 0; j < 4; ++j) {
      u32x4 wv;
#pragma unroll
      for (int p = 0; p < 4; ++p)
        wv[p] = pk2(vb[2 * p][j], vb[2 * p + 1][j]);
      *reinterpret_cast<u32x4*>(&xs[144 + (ulb << 2) + j][uc0]) = wv;
    }
  } else {
#pragma unroll
    for (int j = 0; j < 4; ++j) {
      const int gl = b_gl0 + j;
      u32x4 wv;
#pragma unroll
      for (int p = 0; p < 4; ++p) {
        float lo = 0.f, hi = 0.f;
        if (gl < L_IN) {
          lo = xn[(size_t)(uc0 + 2 * p)     * L_IN + gl];
          hi = xn[(size_t)(uc0 + 2 * p + 1) * L_IN + gl];
        }
        wv[p] = pk2(lo, hi);
      }
      *reinterpret_cast<u32x4*>(&xs[144 + (ulb << 2) + j][uc0]) = wv;
    }
  }
  __syncthreads();

  // ---- store half A (global writes fly under compute-B) -----------------
#pragma unroll
  for (int lt = 0; lt < 8; ++lt) {
    const int l = l0 + (lt << 4) + col;
#pragma unroll
    for (int reg = 0; reg < 4; ++reg)
      out[((size_t)(n * O_OUT + obase + reg) << 14) + l] = acc[lt][reg] + bv[reg];
  }

  // -- half B: out cols l0+128 .. l0+255; rows r = 128 + col + t + 4 + lt*16
#pragma unroll
  for (int lt = 0; lt < 8; ++lt) acc[lt] = (f32x4){0.f, 0.f, 0.f, 0.f};

#pragma unroll
  for (int t = 0; t < KTAP; ++t) {
#pragma unroll
    for (int k = 0; k < 2; ++k) {
      const bf16x8 a = afr[(t << 1) + k];
#pragma unroll
      for (int lt = 0; lt < 8; ++lt) {
        const int r = 128 + col + t + 4 + (lt << 4);
        const bf16x8 b = *reinterpret_cast<const bf16x8*>(&xs[r][(k << 5) + (quad << 3)]);
        acc[lt] = __builtin_amdgcn_mfma_f32_16x16x32_bf16(a, b, acc[lt], 0, 0, 0);
      }
    }
  }

  // ---- store half B -----------------------------------------------------
#pragma unroll
  for (int lt = 0; lt < 8; ++lt) {
    const int l = l0 + 128 + (lt << 4) + col;
#pragma unroll
    for (int reg = 0; reg < 4; ++reg)
      out[((size_t)(n * O_OUT + obase + reg) << 14) + l] = acc[lt][reg] + bv[reg];
  }
}

extern "C" void kernel_launch(void* const* d_in, const int* in_sizes, int n_in,
                              void* d_out, int out_size, void* d_ws, size_t ws_size,
                              hipStream_t stream) {
  const float*    x    = (const float*)d_in[0];
  const float*    w    = (const float*)d_in[1];
  const float*    bias = (const float*)d_in[2];
  float*          out  = (float*)d_out;
  unsigned short* w2   = (unsigned short*)d_ws;   // 73728 B scratch (bf16 weights)

  // 1) rearrange + downcast + pre-scale weights into d_ws (runs every call)
  w_rearrange<<<(KTAP * O_OUT * C_IN + 255) / 256, 256, 0, stream>>>(w, w2);

  // 2) fused conv-as-GEMM: 8 n * 64 L-tiles = 512 blocks
  qconv_kernel<<<8 * (L_IN / LTILE), 256, 0, stream>>>(x, w2, bias, out);
}